// Round 2
// baseline (354.375 us; speedup 1.0000x reference)
//
#include <hip/hip_runtime.h>

typedef short s8v __attribute__((ext_vector_type(8)));
typedef float f4v __attribute__((ext_vector_type(4)));
typedef float f4 __attribute__((ext_vector_type(4)));

#define N_PIX 16384
#define NE    8192
#define EDIM  256
#define ZQ_ELEMS 4194304
#define MARGIN 4.5e-4f
#define NGRP 512           // 16 codes per pruning group

__device__ __forceinline__ float bf2f(unsigned short u) {
    union { unsigned int i; float f; } c; c.i = ((unsigned int)u) << 16; return c.f;
}
__device__ __forceinline__ unsigned short f2bf(float f) {
    unsigned int u = __float_as_uint(f);
    u = (u + 0x7fffu + ((u >> 16) & 1u)) >> 16;   // RNE
    return (unsigned short)u;
}
__device__ __forceinline__ unsigned short f2bf_down(float f) {  // round toward -inf
    unsigned int u = __float_as_uint(f);
    unsigned short b = (unsigned short)(u >> 16);
    if ((u & 0xFFFFu) && (u >> 31)) b += 1;
    return b;
}

// numpy pairwise_sum over 128 squared elements (exact replication: 8
// accumulators, fixed combine tree), f32 RN ops, no FMA contraction.
__device__ __forceinline__ float np_pw128sq(const float* a) {
    float r[8];
    #pragma unroll
    for (int j = 0; j < 8; ++j) r[j] = __fmul_rn(a[j], a[j]);
    for (int i = 8; i < 128; i += 8)
        #pragma unroll
        for (int j = 0; j < 8; ++j) r[j] = __fadd_rn(r[j], __fmul_rn(a[i + j], a[i + j]));
    return __fadd_rn(__fadd_rn(__fadd_rn(r[0], r[1]), __fadd_rn(r[2], r[3])),
                     __fadd_rn(__fadd_rn(r[4], r[5]), __fadd_rn(r[6], r[7])));
}

// K0: cb16 = bf16(cb); esum32[k] = np.sum(cb[k]*cb[k]) in exact np-f32
// pairwise semantics. WS-only writes.
__global__ __launch_bounds__(256) void vq_prep(const float* __restrict__ cb,
                                               unsigned short* __restrict__ cb16,
                                               float* __restrict__ esum32) {
    int t = threadIdx.x;
    int base = blockIdx.x * 64;
    const float* src = cb + (size_t)base * EDIM;
    unsigned short* dst = cb16 + (size_t)base * EDIM;
    for (int i = 0; i < 64; ++i) dst[i * EDIM + t] = f2bf(src[i * EDIM + t]);
    if (t < 64) {
        const float* a = cb + (size_t)(base + t) * EDIM;
        esum32[base + t] = __fadd_rn(np_pw128sq(a), np_pw128sq(a + 128));
    }
}

// K0b: z16[pixel][channel] = bf16(z) -- pixel-major transpose of z so
// phase1g can stage it with clean global_load_lds. LDS-transpose tile
// 64px x 64ch; reads and writes both coalesced; f2bf identical to what
// the old phase1 applied per element (bit-identical MFMA inputs).
__global__ __launch_bounds__(256) void vq_zprep(const float* __restrict__ z,
                                                unsigned short* __restrict__ z16) {
    __shared__ unsigned short zl[64 * 66];   // 66 stride: odd bank step
    int t = threadIdx.x;
    int p0 = (blockIdx.x >> 2) * 64;         // 64 | 1024, tile stays in one image
    int c0 = (blockIdx.x & 3) * 64;
    int b = p0 >> 10, hw0 = p0 & 1023;
    const float* src = z + (((size_t)b * 256 + c0) << 10) + hw0;
    #pragma unroll
    for (int i = 0; i < 16; ++i) {
        int idx = i * 256 + t;
        int ch = idx >> 6, px = idx & 63;    // lanes sweep px: coalesced f32 read
        zl[px * 66 + ch] = f2bf(src[((size_t)ch << 10) + px]);
    }
    __syncthreads();
    #pragma unroll
    for (int i = 0; i < 16; ++i) {
        int idx = i * 256 + t;
        int px = idx >> 6, ch = idx & 63;    // lanes sweep ch: coalesced u16 write
        z16[((size_t)(p0 + px)) * 256 + c0 + ch] = zl[px * 66 + ch];
    }
}

// K1: dual-pipe 256x256-tile GEMM + group-max epilogue.
// A = cb16 (codes, M) read DIRECTLY from global into regs (VMEM/L1/L2 pipe);
// B = z16 (pixels, N) double-buffered in LDS via global_load_lds (LDS pipe).
// Rationale: round-1 kernel was LDS-BW-bound (512 B of ds_read per MFMA ->
// ~26% MfmaUtil cap, matching the measured 24%). Splitting operands across
// the two pipes gives LDS 128 B/MFMA (free) and VMEM 256 B/MFMA (~64% cap);
// the 4 waves of one wave-row issue identical A addresses -> L1 broadcast.
// 8 waves (2M x 4N), per-wave 128x64, acc 8x4 frags. K order (kt,ksub
// ascending 32-chunks) and f2bf inputs identical to round-1 -> gmin is
// bit-identical, phase2 semantics untouched.
__global__ __launch_bounds__(512, 2) void vq_phase1g(const unsigned short* __restrict__ cb16,
                                                     const unsigned short* __restrict__ z16,
                                                     unsigned short* __restrict__ gmin) {
    __shared__ unsigned short lB[2][16384];   // [buf][256 px x 64 k] u16 = 64 KB
    const int t = threadIdx.x;
    const int wave = t >> 6, lane = t & 63;
    const int q = lane >> 4, r = lane & 15;
    const int wr = wave >> 2, wc = wave & 3;      // 2 M-waves x 4 N-waves
    // XCD swizzle (2048 blocks, 8 XCDs, bijective since 2048%8==0):
    // code-tile varies fastest inside an XCD -> cb16 sweep stays L2-hot,
    // consecutive blocks share the same 256-pixel B panel.
    const int sb = (blockIdx.x & 7) * 256 + (blockIdx.x >> 3);
    const int cm0 = (sb & 31) * 256;              // code tile (32 tiles of 256)
    const int pn0 = (sb >> 5) * 256;              // pixel tile (64 tiles of 256)

    // B staging: 2048 16B chunks per buffer, 4 per thread.
    // physical chunk pc holds logical chunk (row, (pc&7)^(row&7)) -- proven
    // zero-conflict swizzle from round 1.
    int goff[4], lof[4];
    #pragma unroll
    for (int j = 0; j < 4; ++j) {
        int pc = j * 512 + t;
        int row = pc >> 3;
        int c = (pc & 7) ^ (row & 7);
        goff[j] = row * 256 + c * 8;   // u16 units; add kt*64 per K-step
        lof[j] = pc * 8;               // linear LDS dest (u16)
    }
    const unsigned short* gB = z16 + (size_t)pn0 * 256;
    // A base for this lane: row cm0 + wr*128 + r, k-col q*8
    const unsigned short* gA = cb16 + (size_t)(cm0 + wr * 128 + r) * 256 + q * 8;

    f4v acc[8][4];
    const f4v zz = {0.f, 0.f, 0.f, 0.f};
    #pragma unroll
    for (int mi = 0; mi < 8; ++mi)
        #pragma unroll
        for (int ni = 0; ni < 4; ++ni) acc[mi][ni] = zz;

#define GLL(g, l) __builtin_amdgcn_global_load_lds( \
        (const __attribute__((address_space(1))) unsigned int*)(g), \
        (__attribute__((address_space(3))) unsigned int*)(l), 16, 0, 0)

    // prologue: stage B kt=0 into buf 0
    #pragma unroll
    for (int j = 0; j < 4; ++j) GLL(gB + goff[j], &lB[0][lof[j]]);

    const int co0 = ((0 * 4 + q) ^ (r & 7)) * 8;   // swizzled B chunk, ksub=0
    const int co1 = ((1 * 4 + q) ^ (r & 7)) * 8;   // ksub=1

    for (int kt = 0; kt < 4; ++kt) {
        int cur = kt & 1;
        __syncthreads();               // drains STAGE(cur) + A loads of kt-1
        if (kt < 3) {                  // prefetch next B K-slice
            int ko = (kt + 1) * 64;
            #pragma unroll
            for (int j = 0; j < 4; ++j) GLL(gB + goff[j] + ko, &lB[cur ^ 1][lof[j]]);
        }
        const unsigned short* Bb = lB[cur];
        #pragma unroll
        for (int ksub = 0; ksub < 2; ++ksub) {
            const int co = ksub ? co1 : co0;
            const int ka = kt * 64 + ksub * 32;    // + q*8 already in gA
            s8v a[8], b[4];
            #pragma unroll
            for (int mi = 0; mi < 8; ++mi)
                a[mi] = *(const s8v*)&gA[(size_t)(mi * 16) * 256 + ka];
            #pragma unroll
            for (int ni = 0; ni < 4; ++ni)
                b[ni] = *(const s8v*)&Bb[(wc * 64 + ni * 16 + r) * 64 + co];
            #pragma unroll
            for (int mi = 0; mi < 8; ++mi)
                #pragma unroll
                for (int ni = 0; ni < 4; ++ni)
                    acc[mi][ni] = __builtin_amdgcn_mfma_f32_16x16x32_bf16(
                        a[mi], b[ni], acc[mi][ni], 0, 0, 0);
        }
    }
#undef GLL

    // epilogue: each 16x16 frag-row is one 16-code group.
    // D layout: col=lane&15 (pixel), row=q*4+reg (code). 3 fmax + xor16 +
    // xor32, q==0 lanes store a coalesced 16-u16 row.
    #pragma unroll
    for (int mi = 0; mi < 8; ++mi) {
        int g = cm0 / 16 + wr * 8 + mi;
        #pragma unroll
        for (int ni = 0; ni < 4; ++ni) {
            f4v a = acc[mi][ni];
            float mx = fmaxf(fmaxf(a[0], a[1]), fmaxf(a[2], a[3]));
            mx = fmaxf(mx, __shfl_xor(mx, 16));
            mx = fmaxf(mx, __shfl_xor(mx, 32));
            if (q == 0)
                gmin[(size_t)g * N_PIX + pn0 + wc * 64 + ni * 16 + r] =
                    f2bf_down(-2.0f * mx);
        }
    }
}

// K1 (fallback, unchanged): used only if workspace can't hold z16.
__global__ __launch_bounds__(512, 2) void vq_phase1(const float* __restrict__ z,
                                                    const unsigned short* __restrict__ cb16,
                                                    unsigned short* __restrict__ gmin) {
    const int t = threadIdx.x;
    const int wave = t >> 6, lane = t & 63;
    const int col = lane & 15, q = lane >> 4;
    const int mb = (blockIdx.x >> 1) * 64;
    const int chalf = blockIdx.x & 1;

    s8v Z[4][8];
    #pragma unroll
    for (int pt = 0; pt < 4; ++pt) {
        int n = mb + pt * 16 + col;
        const float* zb = z + ((size_t)(n >> 10) << 18) + (size_t)(n & 1023);
        #pragma unroll
        for (int c0 = 0; c0 < 8; ++c0) {
            s8v a;
            #pragma unroll
            for (int j = 0; j < 8; ++j) {
                int c = c0 * 32 + q * 8 + j;
                a[j] = (short)f2bf(zb[(size_t)c << 10]);
            }
            Z[pt][c0] = a;
        }
    }

    const int kbase = chalf * 4096 + wave * 512;
    for (int it = 0; it < 16; ++it) {
        int n0 = kbase + it * 32;
        const unsigned short* bb = cb16 + (size_t)(n0 + col) * EDIM + q * 8;
        f4v zz = {0.f, 0.f, 0.f, 0.f};
        f4v acc[4][2];
        #pragma unroll
        for (int pt = 0; pt < 4; ++pt) { acc[pt][0] = zz; acc[pt][1] = zz; }
        #pragma unroll
        for (int c0 = 0; c0 < 8; ++c0) {
            s8v C0 = *(const s8v*)(bb + c0 * 32);
            s8v C1 = *(const s8v*)(bb + 16 * EDIM + c0 * 32);
            #pragma unroll
            for (int pt = 0; pt < 4; ++pt) {
                acc[pt][0] = __builtin_amdgcn_mfma_f32_16x16x32_bf16(C0, Z[pt][c0], acc[pt][0], 0, 0, 0);
                acc[pt][1] = __builtin_amdgcn_mfma_f32_16x16x32_bf16(C1, Z[pt][c0], acc[pt][1], 0, 0, 0);
            }
        }
        int gbase = chalf * 256 + wave * 32 + it * 2;
        #pragma unroll
        for (int pt = 0; pt < 4; ++pt) {
            #pragma unroll
            for (int s = 0; s < 2; ++s) {
                f4v a = acc[pt][s];
                float mx = fmaxf(fmaxf(a[0], a[1]), fmaxf(a[2], a[3]));
                mx = fmaxf(mx, __shfl_xor(mx, 16));
                mx = fmaxf(mx, __shfl_xor(mx, 32));
                if (q == 0)
                    gmin[(size_t)(gbase + s) * N_PIX + mb + pt * 16 + col] =
                        f2bf_down(-2.0f * mx);
            }
        }
    }
}

// K2: rescore candidate 16-code groups replicating np f32 semantics:
// d = f32(f32(zsum + esum[k]) - f32(2 * f32(dot64))), argmin with
// FIRST-INDEX tie-break. 4 waves/block, wave owns pixels 4w..4w+3.
__global__ __launch_bounds__(256) void vq_phase2(const float* __restrict__ z,
                                                 const float* __restrict__ cb,
                                                 const float* __restrict__ esum32,
                                                 const unsigned short* __restrict__ gmin,
                                                 unsigned int* __restrict__ idxw) {
    __shared__ float zt[16 * 260];
    __shared__ unsigned short gm[NGRP * 17];
    __shared__ float zs[16];
    int t = threadIdx.x;
    int wave = t >> 6, lane = t & 63;
    int p0 = blockIdx.x * 16;
    int bb = p0 >> 10, inner = p0 & 1023;

    #pragma unroll
    for (int i = 0; i < 16; ++i) {
        int c = i * 16 + (t >> 4), p = t & 15;
        zt[p * 260 + c] = z[((size_t)(bb * 256 + c) << 10) + inner + p];
    }
    #pragma unroll
    for (int i = 0; i < 32; ++i) {
        int g = i * 16 + (t >> 4), p = t & 15;
        gm[g * 17 + p] = gmin[(size_t)g * N_PIX + p0 + p];
    }
    __syncthreads();
    if (t < 16) {
        const float* a = zt + t * 260;
        zs[t] = __fadd_rn(np_pw128sq(a), np_pw128sq(a + 128));  // np zsum
    }
    __syncthreads();

    #pragma unroll
    for (int pp = 0; pp < 4; ++pp) {
        int p = wave * 4 + pp;
        float lmin = 3.0e38f;
        #pragma unroll
        for (int j = 0; j < 8; ++j) lmin = fminf(lmin, bf2f(gm[(lane * 8 + j) * 17 + p]));
        #pragma unroll
        for (int m = 1; m < 64; m <<= 1) lmin = fminf(lmin, __shfl_xor(lmin, m));
        float thr = lmin + MARGIN;
        float zsp = zs[p];

        float bd = 3.0e38f; int bk = 0x7FFFFFFF;
        for (int j = 0; j < 8; ++j) {
            unsigned long long mask = __ballot(bf2f(gm[(lane * 8 + j) * 17 + p]) <= thr);
            while (mask) {
                int lb = __builtin_ctzll(mask); mask &= mask - 1;
                int g = lb * 8 + j;
                int k = g * 16 + (lane >> 2);
                const f4* cr = (const f4*)(cb + (size_t)k * EDIM) + (lane & 3);
                const f4* zr = (const f4*)(zt + p * 260) + (lane & 3);
                double a0 = 0.0, a1 = 0.0, a2 = 0.0, a3 = 0.0;
                #pragma unroll
                for (int i = 0; i < 16; ++i) {
                    f4 x = zr[i * 4], y = cr[i * 4];
                    a0 = fma((double)x[0], (double)y[0], a0);
                    a1 = fma((double)x[1], (double)y[1], a1);
                    a2 = fma((double)x[2], (double)y[2], a2);
                    a3 = fma((double)x[3], (double)y[3], a3);
                }
                double s = (a0 + a1) + (a2 + a3);
                s += __shfl_xor(s, 1);
                s += __shfl_xor(s, 2);
                float E = (float)s;                                   // einsum f32 surrogate
                float d = __fsub_rn(__fadd_rn(zsp, esum32[k]), __fmul_rn(2.0f, E));
                if (d < bd || (d == bd && k < bk)) { bd = d; bk = k; }
            }
        }
        #pragma unroll
        for (int m = 1; m < 64; m <<= 1) {
            float od = __shfl_xor(bd, m); int ok = __shfl_xor(bk, m);
            if (od < bd || (od == bd && ok < bk)) { bd = od; bk = ok; }
        }
        if (lane == 0) idxw[p0 + p] = (unsigned int)bk;
    }
}

// K3: SOLE final writer of z_q (f32 chunk0, overwrites gmin scratch) and
// indices (f32 chunk2).
__global__ __launch_bounds__(256) void vq_emit(const float* __restrict__ cb,
                                               const float* __restrict__ z,
                                               const unsigned int* __restrict__ idxw,
                                               float* __restrict__ outf,
                                               float* __restrict__ lossw) {
    __shared__ float red[4];
    int t = threadIdx.x;
    int gtid = blockIdx.x * 256 + t;
    if (gtid < N_PIX) outf[ZQ_ELEMS + 1 + gtid] = (float)(idxw[gtid] & (NE - 1));

    float acc = 0.f;
    size_t base = (size_t)blockIdx.x * 16384;
    for (int i = 0; i < 64; ++i) {
        size_t o = base + (size_t)i * 256 + t;
        int b = (int)(o >> 18);
        int c = (int)((o >> 10) & 255);
        int p = (int)(o & 1023);
        int idx = (int)(idxw[b * 1024 + p] & (NE - 1));
        float qv = cb[(size_t)idx * EDIM + c];
        outf[o] = qv;
        float d = qv - z[o];
        acc = fmaf(d, d, acc);
    }
    #pragma unroll
    for (int off = 32; off > 0; off >>= 1) acc += __shfl_down(acc, off);
    if ((t & 63) == 0) red[t >> 6] = acc;
    __syncthreads();
    if (t == 0) atomicAdd(lossw, red[0] + red[1] + red[2] + red[3]);
}

// K4: SOLE writer of loss (f32 chunk1).
__global__ void vq_finalize(const float* __restrict__ lossw, float* __restrict__ loss_out) {
    loss_out[0] = 1.25f * lossw[0] * (1.0f / 4194304.0f);
}

extern "C" void kernel_launch(void* const* d_in, const int* in_sizes, int n_in,
                              void* d_out, int out_size, void* d_ws, size_t ws_size,
                              hipStream_t stream) {
    const float* z  = (const float*)d_in[0];   // f32 [16,256,32,32]
    const float* cb = (const float*)d_in[1];   // f32 [8192,256]
    float* outf = (float*)d_out;               // f32 [z_q | loss | indices]
    // gmin scratch (512 groups x 16384 px, u16 = 16.78 MB) lives in the z_q
    // chunk of d_out between phase1 and phase2; vq_emit overwrites it.
    unsigned short* gmin = (unsigned short*)d_out;

    char* w = (char*)d_ws;
    unsigned short* cb16   = (unsigned short*)w;               //  4,194,304 B
    float*          esum32 = (float*)(w + 4194304);            //     32,768 B
    unsigned int*   idxw   = (unsigned int*)(w + 4227072);     //     65,536 B
    float*          lossw  = (float*)(w + 4292608);            //          4 B (pad to 256)
    unsigned short* z16    = (unsigned short*)(w + 4292864);   //  8,388,608 B -> 12,681,472

    if (ws_size < 4292612) return;  // diagnostic: all-zero out => ws too small
    const bool big_ws = (ws_size >= 12681472);

    hipMemsetAsync(lossw, 0, sizeof(float), stream);
    vq_prep    <<<NE / 64, 256, 0, stream>>>(cb, cb16, esum32);
    if (big_ws) {
        vq_zprep  <<<(N_PIX / 64) * (EDIM / 64), 256, 0, stream>>>(z, z16);
        vq_phase1g<<<(NE / 256) * (N_PIX / 256), 512, 0, stream>>>(cb16, z16, gmin);
    } else {
        vq_phase1 <<<(N_PIX / 64) * 2, 512, 0, stream>>>(z, cb16, gmin);
    }
    vq_phase2  <<<N_PIX / 16, 256, 0, stream>>>(z, cb, esum32, gmin, idxw);
    vq_emit    <<<256, 256, 0, stream>>>(cb, z, idxw, outf, lossw);
    vq_finalize<<<1, 1, 0, stream>>>(lossw, outf + ZQ_ELEMS);
}

// Round 3
// 274.987 us; speedup vs baseline: 1.2887x; 1.2887x over previous
//
#include <hip/hip_runtime.h>

typedef short s8v __attribute__((ext_vector_type(8)));
typedef float f4v __attribute__((ext_vector_type(4)));
typedef float f4 __attribute__((ext_vector_type(4)));

#define N_PIX 16384
#define NE    8192
#define EDIM  256
#define ZQ_ELEMS 4194304
#define MARGIN 4.5e-4f
#define NGRP 512           // 16 codes per pruning group

__device__ __forceinline__ float bf2f(unsigned short u) {
    union { unsigned int i; float f; } c; c.i = ((unsigned int)u) << 16; return c.f;
}
__device__ __forceinline__ unsigned short f2bf(float f) {
    unsigned int u = __float_as_uint(f);
    u = (u + 0x7fffu + ((u >> 16) & 1u)) >> 16;   // RNE
    return (unsigned short)u;
}
__device__ __forceinline__ unsigned short f2bf_down(float f) {  // round toward -inf
    unsigned int u = __float_as_uint(f);
    unsigned short b = (unsigned short)(u >> 16);
    if ((u & 0xFFFFu) && (u >> 31)) b += 1;
    return b;
}

// numpy pairwise_sum over 128 squared elements (exact replication: 8
// accumulators, fixed combine tree), f32 RN ops, no FMA contraction.
__device__ __forceinline__ float np_pw128sq(const float* a) {
    float r[8];
    #pragma unroll
    for (int j = 0; j < 8; ++j) r[j] = __fmul_rn(a[j], a[j]);
    for (int i = 8; i < 128; i += 8)
        #pragma unroll
        for (int j = 0; j < 8; ++j) r[j] = __fadd_rn(r[j], __fmul_rn(a[i + j], a[i + j]));
    return __fadd_rn(__fadd_rn(__fadd_rn(r[0], r[1]), __fadd_rn(r[2], r[3])),
                     __fadd_rn(__fadd_rn(r[4], r[5]), __fadd_rn(r[6], r[7])));
}

// K0: cb16 = bf16(cb); esum32[k] = np.sum(cb[k]*cb[k]) in exact np-f32
// pairwise semantics. WS-only writes.
__global__ __launch_bounds__(256) void vq_prep(const float* __restrict__ cb,
                                               unsigned short* __restrict__ cb16,
                                               float* __restrict__ esum32) {
    int t = threadIdx.x;
    int base = blockIdx.x * 64;
    const float* src = cb + (size_t)base * EDIM;
    unsigned short* dst = cb16 + (size_t)base * EDIM;
    for (int i = 0; i < 64; ++i) dst[i * EDIM + t] = f2bf(src[i * EDIM + t]);
    if (t < 64) {
        const float* a = cb + (size_t)(base + t) * EDIM;
        esum32[base + t] = __fadd_rn(np_pw128sq(a), np_pw128sq(a + 128));
    }
}

// K0b: z16[pixel][channel] = bf16(z) -- pixel-major transpose of z so
// phase1g can stage it with clean global_load_lds. LDS-transpose tile
// 64px x 64ch; reads and writes both coalesced; f2bf identical to what
// the old phase1 applied per element (bit-identical MFMA inputs).
__global__ __launch_bounds__(256) void vq_zprep(const float* __restrict__ z,
                                                unsigned short* __restrict__ z16) {
    __shared__ unsigned short zl[64 * 66];   // 66 stride: odd bank step
    int t = threadIdx.x;
    int p0 = (blockIdx.x >> 2) * 64;         // 64 | 1024, tile stays in one image
    int c0 = (blockIdx.x & 3) * 64;
    int b = p0 >> 10, hw0 = p0 & 1023;
    const float* src = z + (((size_t)b * 256 + c0) << 10) + hw0;
    #pragma unroll
    for (int i = 0; i < 16; ++i) {
        int idx = i * 256 + t;
        int ch = idx >> 6, px = idx & 63;    // lanes sweep px: coalesced f32 read
        zl[px * 66 + ch] = f2bf(src[((size_t)ch << 10) + px]);
    }
    __syncthreads();
    #pragma unroll
    for (int i = 0; i < 16; ++i) {
        int idx = i * 256 + t;
        int px = idx >> 6, ch = idx & 63;    // lanes sweep ch: coalesced u16 write
        z16[((size_t)(p0 + px)) * 256 + c0 + ch] = zl[px * 66 + ch];
    }
}

// K1: 256x256-tile bf16 GEMM, 8-phase counted-vmcnt schedule (T1+T2+T3+T4+T5).
// A = cb16 (codes, M), B = z16 (pixels, N), K=256 (4 K-tiles of BK=64).
// 8 waves (2M x 4N), per-wave 128x64 (8x4 frags). LDS = 2 K-tile buffers x
// (A 32KB + B 32KB) = 128 KB. Each K-tile staged as 4 half-steps (A/B x
// k-half, 2 GLL/thread each), one per phase, into the other buffer.
// Gates: uniform `s_waitcnt vmcnt(4)` (8 loads in flight, oldest 4 = halves
// needed next) at tile head + mid-tile -- never a full drain in the loop.
// Raw s_barrier (no compiler vmcnt(0) drain). LDS layout per operand:
// [ksub][256 rows][4 chunks of 16B], physical chunk = q ^ ((row>>1)&3):
// 2 lanes/bank on ds_read_b128 (free) and stage regions stay GLL-linear
// (involution applied to the pre-swizzled global source).
// K order per acc frag: k ascending 32-chunks, f2bf inputs unchanged ->
// gmin bit-identical to prior rounds.
__global__ __launch_bounds__(512, 2) void vq_phase1g(const unsigned short* __restrict__ cb16,
                                                     const unsigned short* __restrict__ z16,
                                                     unsigned short* __restrict__ gmin) {
    __shared__ unsigned short L[2][32768];   // [buf][A 16K u16 | B 16K u16] = 128 KB
    const int t = threadIdx.x;
    const int wave = t >> 6, lane = t & 63;
    const int q = lane >> 4, r = lane & 15;
    const int wr = wave >> 2, wc = wave & 3;      // 2 M-waves x 4 N-waves
    // XCD swizzle (2048 blocks, 8 XCDs, bijective): code tile fastest within
    // an XCD -> the 256-px B panel stays L2-hot across the code sweep.
    const int sb = ((int)blockIdx.x & 7) * 256 + ((int)blockIdx.x >> 3);
    const int cm0 = (sb & 31) * 256;              // code tile
    const int pn0 = (sb >> 5) * 256;              // pixel tile

    // Staging jobs: one half-step = 256 rows x 32 k of one operand = 16 KB
    // = 2 x 16B slots/thread. Physical slot pc=(row,cph) holds logical
    // chunk lc = cph ^ ((row>>1)&3)  (involution).
    const int pc0 = t, pc1 = t + 512;
    const int row0 = pc0 >> 2, row1 = pc1 >> 2;
    const int lc0 = (pc0 & 3) ^ ((row0 >> 1) & 3);
    const int lc1 = (pc1 & 3) ^ ((row1 >> 1) & 3);
    const int go0 = row0 * 256 + lc0 * 8;   // u16; + kh*32 + ktile*64
    const int go1 = row1 * 256 + lc1 * 8;
    const int ld0 = pc0 * 8;                // u16 within half; + kh*8192
    const int ld1 = pc1 * 8;

    const unsigned short* gA = cb16 + (size_t)cm0 * 256;
    const unsigned short* gB = z16 + (size_t)pn0 * 256;

    f4v acc[8][4];
    const f4v zz = {0.f, 0.f, 0.f, 0.f};
    #pragma unroll
    for (int mi = 0; mi < 8; ++mi)
        #pragma unroll
        for (int ni = 0; ni < 4; ++ni) acc[mi][ni] = zz;

    const int cxo = (q ^ ((r >> 1) & 3)) * 8;     // swizzled chunk offset (u16)

#define GLL(g, l) __builtin_amdgcn_global_load_lds( \
        (const __attribute__((address_space(1))) unsigned int*)(g), \
        (__attribute__((address_space(3))) unsigned int*)(l), 16, 0, 0)
#define STAGE(gbase, lbase, kh, gk) do { \
        GLL((gbase) + go0 + (kh) * 32 + (gk), (lbase) + (kh) * 8192 + ld0); \
        GLL((gbase) + go1 + (kh) * 32 + (gk), (lbase) + (kh) * 8192 + ld1); } while (0)

    // prologue: stage K-tile 0 (4 half-steps, 8 loads) into buf 0
    STAGE(gA, &L[0][0], 0, 0);
    STAGE(gB, &L[0][16384], 0, 0);
    STAGE(gA, &L[0][0], 1, 0);
    STAGE(gB, &L[0][16384], 1, 0);

    for (int kt = 0; kt < 4; ++kt) {
        const int buf = kt & 1;
        const unsigned short* Ab = &L[buf][0];
        const unsigned short* Bb = &L[buf][16384];
        unsigned short* An = &L[buf ^ 1][0];
        unsigned short* Bn = &L[buf ^ 1][16384];
        const int gk = (kt + 1) * 64;
        const bool st = kt < 3;

        // head gate: A-k0,B-k0 of this tile landed (4 younger loads fly on)
        asm volatile("s_waitcnt vmcnt(4)" ::: "memory");
        __builtin_amdgcn_s_barrier();
        __builtin_amdgcn_sched_barrier(0);

        s8v Af[4], Bf[4];
        // ---- P1: ksub0, mi 0-3 (reads B k0 x4 + A k0 x4; stage A-k0') ----
        #pragma unroll
        for (int ni = 0; ni < 4; ++ni)
            Bf[ni] = *(const s8v*)&Bb[(wc * 64 + ni * 16 + r) * 32 + cxo];
        #pragma unroll
        for (int mi = 0; mi < 4; ++mi)
            Af[mi] = *(const s8v*)&Ab[(wr * 128 + mi * 16 + r) * 32 + cxo];
        if (st) STAGE(gA, An, 0, gk);
        __builtin_amdgcn_s_barrier();
        __builtin_amdgcn_sched_barrier(0);
        __builtin_amdgcn_s_setprio(1);
        #pragma unroll
        for (int mi = 0; mi < 4; ++mi)
            #pragma unroll
            for (int ni = 0; ni < 4; ++ni)
                acc[mi][ni] = __builtin_amdgcn_mfma_f32_16x16x32_bf16(
                    Af[mi], Bf[ni], acc[mi][ni], 0, 0, 0);
        __builtin_amdgcn_s_setprio(0);
        __builtin_amdgcn_s_barrier();

        // ---- P2: ksub0, mi 4-7 (reads A k0 x4, B held; stage B-k0') ----
        #pragma unroll
        for (int mi = 0; mi < 4; ++mi)
            Af[mi] = *(const s8v*)&Ab[(wr * 128 + (4 + mi) * 16 + r) * 32 + cxo];
        if (st) STAGE(gB, Bn, 0, gk);
        __builtin_amdgcn_s_barrier();
        __builtin_amdgcn_sched_barrier(0);
        __builtin_amdgcn_s_setprio(1);
        #pragma unroll
        for (int mi = 0; mi < 4; ++mi)
            #pragma unroll
            for (int ni = 0; ni < 4; ++ni)
                acc[4 + mi][ni] = __builtin_amdgcn_mfma_f32_16x16x32_bf16(
                    Af[mi], Bf[ni], acc[4 + mi][ni], 0, 0, 0);
        __builtin_amdgcn_s_setprio(0);
        // mid gate: A-k1,B-k1 of this tile landed
        asm volatile("s_waitcnt vmcnt(4)" ::: "memory");
        __builtin_amdgcn_s_barrier();
        __builtin_amdgcn_sched_barrier(0);

        // ---- P3: ksub1, mi 0-3 (reads B k1 x4 + A k1 x4; stage A-k1') ----
        #pragma unroll
        for (int ni = 0; ni < 4; ++ni)
            Bf[ni] = *(const s8v*)&Bb[8192 + (wc * 64 + ni * 16 + r) * 32 + cxo];
        #pragma unroll
        for (int mi = 0; mi < 4; ++mi)
            Af[mi] = *(const s8v*)&Ab[8192 + (wr * 128 + mi * 16 + r) * 32 + cxo];
        if (st) STAGE(gA, An, 1, gk);
        __builtin_amdgcn_s_barrier();
        __builtin_amdgcn_sched_barrier(0);
        __builtin_amdgcn_s_setprio(1);
        #pragma unroll
        for (int mi = 0; mi < 4; ++mi)
            #pragma unroll
            for (int ni = 0; ni < 4; ++ni)
                acc[mi][ni] = __builtin_amdgcn_mfma_f32_16x16x32_bf16(
                    Af[mi], Bf[ni], acc[mi][ni], 0, 0, 0);
        __builtin_amdgcn_s_setprio(0);
        __builtin_amdgcn_s_barrier();

        // ---- P4: ksub1, mi 4-7 (reads A k1 x4, B held; stage B-k1') ----
        #pragma unroll
        for (int mi = 0; mi < 4; ++mi)
            Af[mi] = *(const s8v*)&Ab[8192 + (wr * 128 + (4 + mi) * 16 + r) * 32 + cxo];
        if (st) STAGE(gB, Bn, 1, gk);
        __builtin_amdgcn_s_barrier();
        __builtin_amdgcn_sched_barrier(0);
        __builtin_amdgcn_s_setprio(1);
        #pragma unroll
        for (int mi = 0; mi < 4; ++mi)
            #pragma unroll
            for (int ni = 0; ni < 4; ++ni)
                acc[4 + mi][ni] = __builtin_amdgcn_mfma_f32_16x16x32_bf16(
                    Af[mi], Bf[ni], acc[4 + mi][ni], 0, 0, 0);
        __builtin_amdgcn_s_setprio(0);
        // loop-head gate of next tile doubles as P4's closing barrier
    }
#undef STAGE
#undef GLL

    // epilogue: each 16x16 frag-row is one 16-code group.
    // D layout: col=lane&15 (pixel), row=q*4+reg (code). 3 fmax + xor16 +
    // xor32, q==0 lanes store a coalesced 16-u16 row.
    #pragma unroll
    for (int mi = 0; mi < 8; ++mi) {
        int g = cm0 / 16 + wr * 8 + mi;
        #pragma unroll
        for (int ni = 0; ni < 4; ++ni) {
            f4v a = acc[mi][ni];
            float mx = fmaxf(fmaxf(a[0], a[1]), fmaxf(a[2], a[3]));
            mx = fmaxf(mx, __shfl_xor(mx, 16));
            mx = fmaxf(mx, __shfl_xor(mx, 32));
            if (q == 0)
                gmin[(size_t)g * N_PIX + pn0 + wc * 64 + ni * 16 + r] =
                    f2bf_down(-2.0f * mx);
        }
    }
}

// K1 (fallback, unchanged): used only if workspace can't hold z16.
__global__ __launch_bounds__(512, 2) void vq_phase1(const float* __restrict__ z,
                                                    const unsigned short* __restrict__ cb16,
                                                    unsigned short* __restrict__ gmin) {
    const int t = threadIdx.x;
    const int wave = t >> 6, lane = t & 63;
    const int col = lane & 15, q = lane >> 4;
    const int mb = (blockIdx.x >> 1) * 64;
    const int chalf = blockIdx.x & 1;

    s8v Z[4][8];
    #pragma unroll
    for (int pt = 0; pt < 4; ++pt) {
        int n = mb + pt * 16 + col;
        const float* zb = z + ((size_t)(n >> 10) << 18) + (size_t)(n & 1023);
        #pragma unroll
        for (int c0 = 0; c0 < 8; ++c0) {
            s8v a;
            #pragma unroll
            for (int j = 0; j < 8; ++j) {
                int c = c0 * 32 + q * 8 + j;
                a[j] = (short)f2bf(zb[(size_t)c << 10]);
            }
            Z[pt][c0] = a;
        }
    }

    const int kbase = chalf * 4096 + wave * 512;
    for (int it = 0; it < 16; ++it) {
        int n0 = kbase + it * 32;
        const unsigned short* bb = cb16 + (size_t)(n0 + col) * EDIM + q * 8;
        f4v zz = {0.f, 0.f, 0.f, 0.f};
        f4v acc[4][2];
        #pragma unroll
        for (int pt = 0; pt < 4; ++pt) { acc[pt][0] = zz; acc[pt][1] = zz; }
        #pragma unroll
        for (int c0 = 0; c0 < 8; ++c0) {
            s8v C0 = *(const s8v*)(bb + c0 * 32);
            s8v C1 = *(const s8v*)(bb + 16 * EDIM + c0 * 32);
            #pragma unroll
            for (int pt = 0; pt < 4; ++pt) {
                acc[pt][0] = __builtin_amdgcn_mfma_f32_16x16x32_bf16(C0, Z[pt][c0], acc[pt][0], 0, 0, 0);
                acc[pt][1] = __builtin_amdgcn_mfma_f32_16x16x32_bf16(C1, Z[pt][c0], acc[pt][1], 0, 0, 0);
            }
        }
        int gbase = chalf * 256 + wave * 32 + it * 2;
        #pragma unroll
        for (int pt = 0; pt < 4; ++pt) {
            #pragma unroll
            for (int s = 0; s < 2; ++s) {
                f4v a = acc[pt][s];
                float mx = fmaxf(fmaxf(a[0], a[1]), fmaxf(a[2], a[3]));
                mx = fmaxf(mx, __shfl_xor(mx, 16));
                mx = fmaxf(mx, __shfl_xor(mx, 32));
                if (q == 0)
                    gmin[(size_t)(gbase + s) * N_PIX + mb + pt * 16 + col] =
                        f2bf_down(-2.0f * mx);
            }
        }
    }
}

// K2: rescore candidate 16-code groups replicating np f32 semantics:
// d = f32(f32(zsum + esum[k]) - f32(2 * f32(dot64))), argmin with
// FIRST-INDEX tie-break. 4 waves/block, wave owns pixels 4w..4w+3.
__global__ __launch_bounds__(256) void vq_phase2(const float* __restrict__ z,
                                                 const float* __restrict__ cb,
                                                 const float* __restrict__ esum32,
                                                 const unsigned short* __restrict__ gmin,
                                                 unsigned int* __restrict__ idxw) {
    __shared__ float zt[16 * 260];
    __shared__ unsigned short gm[NGRP * 17];
    __shared__ float zs[16];
    int t = threadIdx.x;
    int wave = t >> 6, lane = t & 63;
    int p0 = blockIdx.x * 16;
    int bb = p0 >> 10, inner = p0 & 1023;

    #pragma unroll
    for (int i = 0; i < 16; ++i) {
        int c = i * 16 + (t >> 4), p = t & 15;
        zt[p * 260 + c] = z[((size_t)(bb * 256 + c) << 10) + inner + p];
    }
    #pragma unroll
    for (int i = 0; i < 32; ++i) {
        int g = i * 16 + (t >> 4), p = t & 15;
        gm[g * 17 + p] = gmin[(size_t)g * N_PIX + p0 + p];
    }
    __syncthreads();
    if (t < 16) {
        const float* a = zt + t * 260;
        zs[t] = __fadd_rn(np_pw128sq(a), np_pw128sq(a + 128));  // np zsum
    }
    __syncthreads();

    #pragma unroll
    for (int pp = 0; pp < 4; ++pp) {
        int p = wave * 4 + pp;
        float lmin = 3.0e38f;
        #pragma unroll
        for (int j = 0; j < 8; ++j) lmin = fminf(lmin, bf2f(gm[(lane * 8 + j) * 17 + p]));
        #pragma unroll
        for (int m = 1; m < 64; m <<= 1) lmin = fminf(lmin, __shfl_xor(lmin, m));
        float thr = lmin + MARGIN;
        float zsp = zs[p];

        float bd = 3.0e38f; int bk = 0x7FFFFFFF;
        for (int j = 0; j < 8; ++j) {
            unsigned long long mask = __ballot(bf2f(gm[(lane * 8 + j) * 17 + p]) <= thr);
            while (mask) {
                int lb = __builtin_ctzll(mask); mask &= mask - 1;
                int g = lb * 8 + j;
                int k = g * 16 + (lane >> 2);
                const f4* cr = (const f4*)(cb + (size_t)k * EDIM) + (lane & 3);
                const f4* zr = (const f4*)(zt + p * 260) + (lane & 3);
                double a0 = 0.0, a1 = 0.0, a2 = 0.0, a3 = 0.0;
                #pragma unroll
                for (int i = 0; i < 16; ++i) {
                    f4 x = zr[i * 4], y = cr[i * 4];
                    a0 = fma((double)x[0], (double)y[0], a0);
                    a1 = fma((double)x[1], (double)y[1], a1);
                    a2 = fma((double)x[2], (double)y[2], a2);
                    a3 = fma((double)x[3], (double)y[3], a3);
                }
                double s = (a0 + a1) + (a2 + a3);
                s += __shfl_xor(s, 1);
                s += __shfl_xor(s, 2);
                float E = (float)s;                                   // einsum f32 surrogate
                float d = __fsub_rn(__fadd_rn(zsp, esum32[k]), __fmul_rn(2.0f, E));
                if (d < bd || (d == bd && k < bk)) { bd = d; bk = k; }
            }
        }
        #pragma unroll
        for (int m = 1; m < 64; m <<= 1) {
            float od = __shfl_xor(bd, m); int ok = __shfl_xor(bk, m);
            if (od < bd || (od == bd && ok < bk)) { bd = od; bk = ok; }
        }
        if (lane == 0) idxw[p0 + p] = (unsigned int)bk;
    }
}

// K3: SOLE final writer of z_q (f32 chunk0, overwrites gmin scratch) and
// indices (f32 chunk2).
__global__ __launch_bounds__(256) void vq_emit(const float* __restrict__ cb,
                                               const float* __restrict__ z,
                                               const unsigned int* __restrict__ idxw,
                                               float* __restrict__ outf,
                                               float* __restrict__ lossw) {
    __shared__ float red[4];
    int t = threadIdx.x;
    int gtid = blockIdx.x * 256 + t;
    if (gtid < N_PIX) outf[ZQ_ELEMS + 1 + gtid] = (float)(idxw[gtid] & (NE - 1));

    float acc = 0.f;
    size_t base = (size_t)blockIdx.x * 16384;
    for (int i = 0; i < 64; ++i) {
        size_t o = base + (size_t)i * 256 + t;
        int b = (int)(o >> 18);
        int c = (int)((o >> 10) & 255);
        int p = (int)(o & 1023);
        int idx = (int)(idxw[b * 1024 + p] & (NE - 1));
        float qv = cb[(size_t)idx * EDIM + c];
        outf[o] = qv;
        float d = qv - z[o];
        acc = fmaf(d, d, acc);
    }
    #pragma unroll
    for (int off = 32; off > 0; off >>= 1) acc += __shfl_down(acc, off);
    if ((t & 63) == 0) red[t >> 6] = acc;
    __syncthreads();
    if (t == 0) atomicAdd(lossw, red[0] + red[1] + red[2] + red[3]);
}

// K4: SOLE writer of loss (f32 chunk1).
__global__ void vq_finalize(const float* __restrict__ lossw, float* __restrict__ loss_out) {
    loss_out[0] = 1.25f * lossw[0] * (1.0f / 4194304.0f);
}

extern "C" void kernel_launch(void* const* d_in, const int* in_sizes, int n_in,
                              void* d_out, int out_size, void* d_ws, size_t ws_size,
                              hipStream_t stream) {
    const float* z  = (const float*)d_in[0];   // f32 [16,256,32,32]
    const float* cb = (const float*)d_in[1];   // f32 [8192,256]
    float* outf = (float*)d_out;               // f32 [z_q | loss | indices]
    // gmin scratch (512 groups x 16384 px, u16 = 16.78 MB) lives in the z_q
    // chunk of d_out between phase1 and phase2; vq_emit overwrites it.
    unsigned short* gmin = (unsigned short*)d_out;

    char* w = (char*)d_ws;
    unsigned short* cb16   = (unsigned short*)w;               //  4,194,304 B
    float*          esum32 = (float*)(w + 4194304);            //     32,768 B
    unsigned int*   idxw   = (unsigned int*)(w + 4227072);     //     65,536 B
    float*          lossw  = (float*)(w + 4292608);            //          4 B (pad to 256)
    unsigned short* z16    = (unsigned short*)(w + 4292864);   //  8,388,608 B -> 12,681,472

    if (ws_size < 4292612) return;  // diagnostic: all-zero out => ws too small
    const bool big_ws = (ws_size >= 12681472);

    hipMemsetAsync(lossw, 0, sizeof(float), stream);
    vq_prep    <<<NE / 64, 256, 0, stream>>>(cb, cb16, esum32);
    if (big_ws) {
        vq_zprep  <<<(N_PIX / 64) * (EDIM / 64), 256, 0, stream>>>(z, z16);
        vq_phase1g<<<(NE / 256) * (N_PIX / 256), 512, 0, stream>>>(cb16, z16, gmin);
    } else {
        vq_phase1 <<<(N_PIX / 64) * 2, 512, 0, stream>>>(z, cb16, gmin);
    }
    vq_phase2  <<<N_PIX / 16, 256, 0, stream>>>(z, cb, esum32, gmin, idxw);
    vq_emit    <<<256, 256, 0, stream>>>(cb, z, idxw, outf, lossw);
    vq_finalize<<<1, 1, 0, stream>>>(lossw, outf + ZQ_ELEMS);
}